// Round 1
// baseline (1768.239 us; speedup 1.0000x reference)
//
#include <hip/hip_runtime.h>

#define NBATCH 4
#define NPTS   16384
#define BN     (NBATCH * NPTS)   // 65536 points total
#define R2V    16384             // 128*128 bins per batch

// ---------- order-preserving float<->uint encoding for atomic max ----------
__device__ __forceinline__ unsigned fenc(float f) {
  unsigned u = __float_as_uint(f);
  return (u & 0x80000000u) ? ~u : (u | 0x80000000u);
}
__device__ __forceinline__ float fdec(unsigned u) {
  unsigned b = (u & 0x80000000u) ? (u & 0x7fffffffu) : ~u;
  return __uint_as_float(b);
}

// ---------- utility kernels ----------
__global__ void k_zero(float* __restrict__ p, int n) {
  int g = blockIdx.x * 256 + threadIdx.x;
  if (g < n) p[g] = 0.f;
}

__global__ void k_idx(const float* __restrict__ pts, int* __restrict__ idx,
                      float* __restrict__ cnt) {
  int g = blockIdx.x * 256 + threadIdx.x;
  if (g >= BN) return;
  int b = g >> 14;
  float px = pts[g * 3 + 0], py = pts[g * 3 + 1];
  int xi = (int)(px * 128.f); xi = xi < 0 ? 0 : (xi > 127 ? 127 : xi);
  int yi = (int)(py * 128.f); yi = yi < 0 ? 0 : (yi > 127 ? 127 : yi);
  int id = xi + (yi << 7);
  idx[g] = id;
  atomicAdd(&cnt[(b << 14) + id], 1.f);
}

// transpose all weight matrices to [k][n] layout once per launch (tiny)
__global__ void k_wT(const float* __restrict__ fc0w, const float* __restrict__ scw,
                     const float* __restrict__ fc1w, const float* __restrict__ fccw,
                     float* __restrict__ fc0T, float* __restrict__ scT,
                     float* __restrict__ fc1T, float* __restrict__ fccT) {
  int g = blockIdx.x * 256 + threadIdx.x;
  if (g < 5 * 128 * 256) {               // fc0 and sc share shape (5,128,256)
    int blk = g >> 15, rem = g & 32767, r = rem >> 8, k = rem & 255;
    fc0T[(blk << 15) + (k << 7) + r] = fc0w[g];
    scT [(blk << 15) + (k << 7) + r] = scw[g];
  } else {
    int g2 = g - 5 * 128 * 256;
    if (g2 < 5 * 128 * 128) {            // fc1 (5,128,128)
      int blk = g2 >> 14, rem = g2 & 16383, r = rem >> 7, k = rem & 127;
      fc1T[(blk << 14) + (k << 7) + r] = fc1w[g2];
    } else {
      int g3 = g2 - 5 * 128 * 128;
      if (g3 < 128 * 128) {              // fc_c (128,128)
        int r = g3 >> 7, k = g3 & 127;
        fccT[(k << 7) + r] = fccw[g3];
      }
    }
  }
}

// segment max via encoded atomicMax; bins pre-zeroed (0 == "-inf" sentinel)
__global__ void k_pool(const float* __restrict__ net, const int* __restrict__ idx,
                       unsigned* __restrict__ bins) {
  int g = blockIdx.x * 256 + threadIdx.x;   // covers BN*128 = 8388608 exactly
  int c = g & 127, pn = g >> 7;
  int b = pn >> 14;
  unsigned e = fenc(net[g]);
  atomicMax(&bins[(((b << 14) + idx[pn]) << 7) + c], e);
}

// ---------- GEMM helpers ----------
__device__ __forceinline__ void stage_wb16(float* __restrict__ wb,
                                           const float* __restrict__ wsrc, int tid) {
  #pragma unroll
  for (int t = 0; t < 2; ++t) {
    int f4 = tid + (t << 8);               // 512 float4 = 16x128 chunk
    *(float4*)&wb[f4 << 2] = *(const float4*)&wsrc[f4 << 2];
  }
}

template <bool RELU>
__device__ __forceinline__ void mac16(const float* __restrict__ xsb,
                                      const float* __restrict__ wbb,
                                      float acc[2][8]) {
  #pragma unroll
  for (int k = 0; k < 16; ++k) {
    float a0 = xsb[k * 33], a1 = xsb[k * 33 + 1];
    if (RELU) { a0 = fmaxf(a0, 0.f); a1 = fmaxf(a1, 0.f); }
    float4 bp = *(const float4*)&wbb[k << 7];
    float4 bq = *(const float4*)&wbb[(k << 7) + 4];
    float bv[8] = {bp.x, bp.y, bp.z, bp.w, bq.x, bq.y, bq.z, bq.w};
    #pragma unroll
    for (int j = 0; j < 8; ++j) {
      acc[0][j] = fmaf(a0, bv[j], acc[0][j]);
      acc[1][j] = fmaf(a1, bv[j], acc[1][j]);
    }
  }
}

// ---------- fused ResnetBlockFC ----------
// SRC==0: x = fc_pos(points) (K=256, computed in staging)
// SRC==1: x = [net | decode(bins[idx])] (K=256)
// out = x@wsT + b1 + relu(h)@w1T, h = relu(x)@w0T + b0
template <int SRC>
__launch_bounds__(256)
__global__ void k_resblock(const float* __restrict__ src, const unsigned* __restrict__ bins,
                           const int* __restrict__ idx,
                           const float* __restrict__ posw, const float* __restrict__ posb,
                           const float* __restrict__ w0T, const float* __restrict__ b0,
                           const float* __restrict__ w1T, const float* __restrict__ b1,
                           const float* __restrict__ wsT,
                           float* __restrict__ net_out) {
  __shared__ float xs[256 * 33];   // x^T tile, stride 33 breaks bank conflicts
  __shared__ float hs[128 * 33];   // relu(h)^T tile
  __shared__ float wb[16 * 128];   // weight chunk [k][n]
  const int tid = threadIdx.x;
  const int p0 = blockIdx.x << 5;  // 32 points per workgroup
  const int b = p0 >> 14;

  if (SRC == 0) {
    const int m = tid & 31, cb = (tid >> 5) << 5;
    const float* pp = &src[(size_t)(p0 + m) * 3];
    float px = pp[0], py = pp[1], pz = pp[2];
    #pragma unroll 4
    for (int cc = 0; cc < 32; ++cc) {
      int c = cb + cc;
      float v = fmaf(posw[c * 3 + 0], px,
               fmaf(posw[c * 3 + 1], py,
               fmaf(posw[c * 3 + 2], pz, posb[c])));
      xs[c * 33 + m] = v;
    }
  } else {
    const int lane = tid & 31, slot = tid >> 5;
    for (int r = slot; r < 32; r += 8) {
      float4 v = *(const float4*)&src[(size_t)(p0 + r) * 128 + (lane << 2)];
      int cb = lane << 2;
      xs[(cb + 0) * 33 + r] = v.x; xs[(cb + 1) * 33 + r] = v.y;
      xs[(cb + 2) * 33 + r] = v.z; xs[(cb + 3) * 33 + r] = v.w;
    }
    for (int r = slot; r < 32; r += 8) {
      int rb = idx[p0 + r];
      uint4 u = *(const uint4*)&bins[(size_t)(((b << 14) + rb) << 7) + (lane << 2)];
      int cb = 128 + (lane << 2);
      xs[(cb + 0) * 33 + r] = fdec(u.x); xs[(cb + 1) * 33 + r] = fdec(u.y);
      xs[(cb + 2) * 33 + r] = fdec(u.z); xs[(cb + 3) * 33 + r] = fdec(u.w);
    }
  }

  const int tn = tid & 15, tm = tid >> 4;
  const int n8 = tn << 3, m2 = tm << 1;

  // GEMM1: h = relu(x) @ w0T + b0
  float acc[2][8];
  #pragma unroll
  for (int j = 0; j < 8; ++j) { float v = b0[n8 + j]; acc[0][j] = v; acc[1][j] = v; }
  for (int kc = 0; kc < 256; kc += 16) {
    __syncthreads();                               // wb safe to overwrite (also fences xs staging on first iter)
    stage_wb16(wb, w0T + ((size_t)kc << 7), tid);
    __syncthreads();
    mac16<true>(&xs[kc * 33 + m2], &wb[n8], acc);
  }

  // store relu(h) to LDS
  #pragma unroll
  for (int j = 0; j < 8; ++j) {
    hs[(n8 + j) * 33 + m2]     = fmaxf(acc[0][j], 0.f);
    hs[(n8 + j) * 33 + m2 + 1] = fmaxf(acc[1][j], 0.f);
  }

  // GEMM2: out = x @ wsT + relu(h) @ w1T + b1
  float acc2[2][8];
  #pragma unroll
  for (int j = 0; j < 8; ++j) { float v = b1[n8 + j]; acc2[0][j] = v; acc2[1][j] = v; }
  for (int kc = 0; kc < 256; kc += 16) {
    __syncthreads();
    stage_wb16(wb, wsT + ((size_t)kc << 7), tid);
    __syncthreads();
    mac16<false>(&xs[kc * 33 + m2], &wb[n8], acc2);
  }
  for (int kc = 0; kc < 128; kc += 16) {
    __syncthreads();
    stage_wb16(wb, w1T + ((size_t)kc << 7), tid);
    __syncthreads();
    mac16<false>(&hs[kc * 33 + m2], &wb[n8], acc2);
  }

  #pragma unroll
  for (int i = 0; i < 2; ++i) {
    float* orow = &net_out[(size_t)(p0 + m2 + i) * 128 + n8];
    *(float4*)orow       = make_float4(acc2[i][0], acc2[i][1], acc2[i][2], acc2[i][3]);
    *(float4*)(orow + 4) = make_float4(acc2[i][4], acc2[i][5], acc2[i][6], acc2[i][7]);
  }
}

// ---------- final linear + scatter-sum ----------
__launch_bounds__(256)
__global__ void k_fcc(const float* __restrict__ net, const int* __restrict__ idx,
                      const float* __restrict__ fccT, const float* __restrict__ fccb,
                      float* __restrict__ sums) {
  __shared__ float xs[128 * 33];
  __shared__ float wb[16 * 128];
  const int tid = threadIdx.x;
  const int p0 = blockIdx.x << 5;
  const int b = p0 >> 14;
  {
    const int lane = tid & 31, slot = tid >> 5;
    for (int r = slot; r < 32; r += 8) {
      float4 v = *(const float4*)&net[(size_t)(p0 + r) * 128 + (lane << 2)];
      int cb = lane << 2;
      xs[(cb + 0) * 33 + r] = fmaxf(v.x, 0.f); xs[(cb + 1) * 33 + r] = fmaxf(v.y, 0.f);
      xs[(cb + 2) * 33 + r] = fmaxf(v.z, 0.f); xs[(cb + 3) * 33 + r] = fmaxf(v.w, 0.f);
    }
  }
  const int tn = tid & 15, tm = tid >> 4;
  const int n8 = tn << 3, m2 = tm << 1;
  float acc[2][8];
  #pragma unroll
  for (int j = 0; j < 8; ++j) { float v = fccb[n8 + j]; acc[0][j] = v; acc[1][j] = v; }
  for (int kc = 0; kc < 128; kc += 16) {
    __syncthreads();
    stage_wb16(wb, fccT + ((size_t)kc << 7), tid);
    __syncthreads();
    mac16<false>(&xs[kc * 33 + m2], &wb[n8], acc);
  }
  #pragma unroll
  for (int i = 0; i < 2; ++i) {
    int m = p0 + m2 + i;
    int r = idx[m];
    float* srow = &sums[(size_t)(((b << 14) + r) << 7) + n8];
    #pragma unroll
    for (int j = 0; j < 8; ++j) atomicAdd(&srow[j], acc[i][j]);
  }
}

// ---------- divide by counts + transpose (B,R2,C) -> (B,C,R2) ----------
__launch_bounds__(256)
__global__ void k_finalize(const float* __restrict__ sums, const float* __restrict__ cnt,
                           float* __restrict__ out) {
  __shared__ float t[64 * 65];
  __shared__ float rc[64];
  const int bid = blockIdx.x;                 // 4 * 256 * 2 = 2048
  const int ct = bid & 1, rt = (bid >> 1) & 255, b = bid >> 9;
  const int r0 = rt << 6, c0 = ct << 6;
  const int tid = threadIdx.x, l16 = tid & 15, sl = tid >> 4;
  for (int rr = sl; rr < 64; rr += 16) {
    float4 v = *(const float4*)&sums[(size_t)((b << 14) + r0 + rr) * 128 + c0 + (l16 << 2)];
    int cb = l16 << 2;
    t[rr * 65 + cb + 0] = v.x; t[rr * 65 + cb + 1] = v.y;
    t[rr * 65 + cb + 2] = v.z; t[rr * 65 + cb + 3] = v.w;
  }
  if (tid < 64) rc[tid] = 1.f / fmaxf(cnt[(b << 14) + r0 + tid], 1.f);
  __syncthreads();
  for (int cc = sl; cc < 64; cc += 16) {
    int c = c0 + cc;
    int rb = l16 << 2;
    float4 o = make_float4(t[(rb + 0) * 65 + cc] * rc[rb + 0],
                           t[(rb + 1) * 65 + cc] * rc[rb + 1],
                           t[(rb + 2) * 65 + cc] * rc[rb + 2],
                           t[(rb + 3) * 65 + cc] * rc[rb + 3]);
    *(float4*)&out[(size_t)((b << 7) + c) * 16384 + r0 + rb] = o;
  }
}

// ---------- host launch ----------
extern "C" void kernel_launch(void* const* d_in, const int* in_sizes, int n_in,
                              void* d_out, int out_size, void* d_ws, size_t ws_size,
                              hipStream_t stream) {
  const float* points = (const float*)d_in[0];
  const float* posw   = (const float*)d_in[1];
  const float* posb   = (const float*)d_in[2];
  const float* fc0w   = (const float*)d_in[3];
  const float* fc0b   = (const float*)d_in[4];
  const float* fc1w   = (const float*)d_in[5];
  const float* fc1b   = (const float*)d_in[6];
  const float* scw    = (const float*)d_in[7];
  const float* fccw   = (const float*)d_in[8];
  const float* fccb   = (const float*)d_in[9];
  float* outp = (float*)d_out;

  // workspace layout (floats): total ~98.1 MB
  float* ws    = (float*)d_ws;
  float* net_a = ws;                                   // 8,388,608
  float* net_b = net_a + (size_t)BN * 128;             // 8,388,608
  unsigned* bins = (unsigned*)(net_b + (size_t)BN * 128); // 8,388,608 (aliased as sums)
  int*   idxp  = (int*)((float*)bins + (size_t)8388608);  // 65,536
  float* cnt   = (float*)(idxp + BN);                  // 65,536
  float* fc0T  = cnt + 65536;                          // 5*256*128
  float* scT   = fc0T + 163840;                        // 5*256*128
  float* fc1T  = scT + 163840;                         // 5*128*128
  float* fccT  = fc1T + 81920;                         // 128*128

  k_zero<<<256, 256, 0, stream>>>(cnt, 65536);
  k_idx<<<256, 256, 0, stream>>>(points, idxp, cnt);
  k_wT<<<1024, 256, 0, stream>>>(fc0w, scw, fc1w, fccw, fc0T, scT, fc1T, fccT);

  // resblock 0: x = fc_pos(points)
  k_resblock<0><<<2048, 256, 0, stream>>>(points, (const unsigned*)nullptr, idxp,
                                          posw, posb,
                                          fc0T, fc0b, fc1T, fc1b, scT, net_a);
  float* cur = net_a;
  float* nxt = net_b;
  for (int k = 1; k < 5; ++k) {
    k_zero<<<32768, 256, 0, stream>>>((float*)bins, 8388608);   // encoded "-inf"
    k_pool<<<32768, 256, 0, stream>>>(cur, idxp, bins);
    k_resblock<1><<<2048, 256, 0, stream>>>(cur, bins, idxp,
                                            (const float*)nullptr, (const float*)nullptr,
                                            fc0T + (size_t)k * 32768, fc0b + k * 128,
                                            fc1T + (size_t)k * 16384, fc1b + k * 128,
                                            scT + (size_t)k * 32768, nxt);
    float* tsw = cur; cur = nxt; nxt = tsw;
  }

  // reuse bins buffer as scatter-sum accumulator
  k_zero<<<32768, 256, 0, stream>>>((float*)bins, 8388608);
  k_fcc<<<2048, 256, 0, stream>>>(cur, idxp, fccT, fccb, (float*)bins);
  k_finalize<<<2048, 256, 0, stream>>>((const float*)bins, cnt, outp);
}

// Round 3
// 455.386 us; speedup vs baseline: 3.8829x; 3.8829x over previous
//
#include <hip/hip_runtime.h>

#define NBATCH 4
#define NPTS   16384
#define BN     (NBATCH * NPTS)   // 65536 points

typedef __attribute__((ext_vector_type(8))) _Float16 half8;
typedef __attribute__((ext_vector_type(4))) float f32x4;

#define INV4096 2.44140625e-4f

// ---------- order-preserving float<->uint encoding for atomic max ----------
__device__ __forceinline__ unsigned fenc(float f) {
  unsigned u = __float_as_uint(f);
  return (u & 0x80000000u) ? ~u : (u | 0x80000000u);
}
__device__ __forceinline__ float fdec(unsigned u) {
  unsigned b = (u & 0x80000000u) ? (u & 0x7fffffffu) : ~u;
  return __uint_as_float(b);
}

// ---------- split-fp16 (hi + lo*2^-12 ~ fp32 accuracy) ----------
// hi kept normal-or-signed-zero; lo scaled by 4096 so it stays normal.
__device__ __forceinline__ void splith(float x, _Float16& h, _Float16& l) {
  float ax = __builtin_fabsf(x);
  if (ax < 6.1035e-5f) {
    unsigned short sb = (unsigned short)((__float_as_uint(x) >> 16) & 0x8000u);
    h = __builtin_bit_cast(_Float16, sb);          // +/-0 preserves sign for relu
    l = (_Float16)(x * 4096.f);
  } else {
    _Float16 hh = (_Float16)x;
    h = hh;
    l = (_Float16)((x - (float)hh) * 4096.f);      // x-hh exact (Sterbenz)
  }
}
__device__ __forceinline__ void splith8(const float v[8], half8& hi, half8& lo) {
  #pragma unroll
  for (int j = 0; j < 8; ++j) { _Float16 h, l; splith(v[j], h, l); hi[j] = h; lo[j] = l; }
}

// zero halves of v where the corresponding half of sgn has its sign bit set
__device__ __forceinline__ half8 relu8(half8 sgn, half8 v) {
  uint4 s = __builtin_bit_cast(uint4, sgn);
  uint4 x = __builtin_bit_cast(uint4, v);
  unsigned* sp = (unsigned*)&s;
  unsigned* xp = (unsigned*)&x;
  uint4 out;
  unsigned* op = (unsigned*)&out;
  #pragma unroll
  for (int w = 0; w < 4; ++w) {
    unsigned m = sp[w] & 0x80008000u;
    unsigned drop = (m - (m >> 15)) | m;   // 0xFFFF per negative half
    op[w] = xp[w] & ~drop;
  }
  return __builtin_bit_cast(half8, out);
}

// ---------- utility kernels ----------
__global__ void k_zero4(float4* __restrict__ p, int n4) {
  int g = blockIdx.x * 256 + threadIdx.x;
  if (g < n4) p[g] = make_float4(0.f, 0.f, 0.f, 0.f);
}

__global__ void k_idx(const float* __restrict__ pts, int* __restrict__ idx,
                      float* __restrict__ cnt) {
  int g = blockIdx.x * 256 + threadIdx.x;
  if (g >= BN) return;
  int b = g >> 14;
  float px = pts[g * 3 + 0], py = pts[g * 3 + 1];
  int xi = (int)(px * 128.f); xi = xi < 0 ? 0 : (xi > 127 ? 127 : xi);
  int yi = (int)(py * 128.f); yi = yi < 0 ? 0 : (yi > 127 ? 127 : yi);
  int id = xi + (yi << 7);
  idx[g] = id;
  atomicAdd(&cnt[(b << 14) + id], 1.f);
}

// ---------- pack weights into frag-ordered split-fp16 planes ----------
// slot = (t*(K/32) + s)*64 + lane; holds 8 f16: w[t*16+(lane&15)][s*32+(lane>>4)*8+j]
// hi plane [0..N*K), lo plane [N*K..2*N*K)
__device__ __forceinline__ void pack_slot(const float* __restrict__ src, int K,
                                          _Float16* __restrict__ dhi, int NK,
                                          int slot) {
  int fpt = (K >> 5) << 6;                 // frags per 16-row tile
  int t = slot / fpt, rem = slot - t * fpt;
  int s = rem >> 6, lane = rem & 63;
  int row = (t << 4) + (lane & 15);
  int k0 = (s << 5) + ((lane >> 4) << 3);
  float v[8];
  #pragma unroll
  for (int j = 0; j < 8; ++j) v[j] = src[row * K + k0 + j];
  half8 hi, lo; splith8(v, hi, lo);
  *(half8*)&dhi[(size_t)slot << 3] = hi;
  *(half8*)&dhi[((size_t)slot << 3) + NK] = lo;
}

__global__ void k_pack(const float* __restrict__ fc0w, const float* __restrict__ scw,
                       const float* __restrict__ fc1w, const float* __restrict__ fccw,
                       _Float16* __restrict__ wp) {
  int g = blockIdx.x * 256 + threadIdx.x;     // total 53248 slots
  if (g < 20480) {                            // fc0: 5 layers x 4096 slots
    int l = g >> 12, slot = g & 4095;
    pack_slot(fc0w + (size_t)l * 32768, 256, wp + (size_t)l * 65536, 32768, slot);
  } else if (g < 40960) {                     // sc
    int g2 = g - 20480; int l = g2 >> 12, slot = g2 & 4095;
    pack_slot(scw + (size_t)l * 32768, 256, wp + 327680 + (size_t)l * 65536, 32768, slot);
  } else if (g < 51200) {                     // fc1: 5 x 2048 slots
    int g2 = g - 40960; int l = g2 >> 11, slot = g2 & 2047;
    pack_slot(fc1w + (size_t)l * 16384, 128, wp + 655360 + (size_t)l * 32768, 16384, slot);
  } else {                                    // fc_c: 2048 slots
    int slot = g - 51200;
    pack_slot(fccw, 128, wp + 819200, 16384, slot);
  }
}

// ---------- fused ResnetBlockFC (MFMA, split-fp16) ----------
template <int SRC, int POOL>
__launch_bounds__(256, 2)
__global__ void k_rb(const float* __restrict__ pts, const unsigned* __restrict__ binsIn,
                     unsigned* __restrict__ binsOut, const int* __restrict__ idx,
                     const float* __restrict__ posw, const float* __restrict__ posb,
                     const _Float16* __restrict__ w0p, const float* __restrict__ b0,
                     const _Float16* __restrict__ w1p, const float* __restrict__ b1,
                     const _Float16* __restrict__ wsp,
                     float* net) {
  extern __shared__ _Float16 smem[];          // 64 KB
  _Float16* Ahi = smem;                       // 16384 f16
  _Float16* Alo = smem + 16384;
  const int tid = threadIdx.x;
  const int lane = tid & 63, wave = tid >> 6;
  const int p0 = blockIdx.x << 6;
  const int b = p0 >> 14;

  // ---- stage x (hi/lo frag planes, XOR-swizzled) ----
  #pragma unroll
  for (int i = 0; i < 8; ++i) {
    int sidx = tid + (i << 8);
    int m = sidx >> 5, kslot = sidx & 31, k0 = kslot << 3;
    float v[8];
    if (SRC == 0) {
      const float* pp = &pts[(size_t)(p0 + m) * 3];
      float px = pp[0], py = pp[1], pz = pp[2];
      #pragma unroll
      for (int j = 0; j < 8; ++j) {
        int c = k0 + j;
        v[j] = fmaf(posw[c * 3 + 0], px,
               fmaf(posw[c * 3 + 1], py,
               fmaf(posw[c * 3 + 2], pz, posb[c])));
      }
    } else {
      if (kslot < 16) {
        float4 a = *(const float4*)&net[(size_t)(p0 + m) * 128 + k0];
        float4 c = *(const float4*)&net[(size_t)(p0 + m) * 128 + k0 + 4];
        v[0] = a.x; v[1] = a.y; v[2] = a.z; v[3] = a.w;
        v[4] = c.x; v[5] = c.y; v[6] = c.z; v[7] = c.w;
      } else {
        int rb_ = idx[p0 + m];
        const unsigned* brow = &binsIn[(size_t)(((b << 14) + rb_) << 7) + (k0 - 128)];
        uint4 a = *(const uint4*)brow;
        uint4 c = *(const uint4*)(brow + 4);
        v[0] = fdec(a.x); v[1] = fdec(a.y); v[2] = fdec(a.z); v[3] = fdec(a.w);
        v[4] = fdec(c.x); v[5] = fdec(c.y); v[6] = fdec(c.z); v[7] = fdec(c.w);
      }
    }
    half8 hi, lo; splith8(v, hi, lo);
    int mt = m >> 4, mm = m & 15, s = kslot >> 2, quad = kslot & 3;
    int ln = mm + (quad << 4), kg = (mt << 3) + s;
    int u = (kg << 6) + (ln ^ (kg & 7));
    *(half8*)&Ahi[u << 3] = hi;
    *(half8*)&Alo[u << 3] = lo;
  }
  __syncthreads();

  // ---- combined K-loop: h = relu(x)@w0+b0 ; s = x@ws+b1 (main + cross acc) ----
  f32x4 hm[4][2], hc[4][2], so[4][2], sc[4][2];
  {
    int col = lane & 15;
    #pragma unroll
    for (int nt = 0; nt < 2; ++nt) {
      float bv0 = b0[(wave << 5) + (nt << 4) + col];
      float bv1 = b1[(wave << 5) + (nt << 4) + col];
      #pragma unroll
      for (int mt = 0; mt < 4; ++mt) {
        hm[mt][nt] = (f32x4){bv0, bv0, bv0, bv0};
        so[mt][nt] = (f32x4){bv1, bv1, bv1, bv1};
        hc[mt][nt] = (f32x4){0.f, 0.f, 0.f, 0.f};
        sc[mt][nt] = (f32x4){0.f, 0.f, 0.f, 0.f};
      }
    }
  }
  const _Float16* w0lo = w0p + 32768;
  const _Float16* wslo = wsp + 32768;
  for (int ks = 0; ks < 8; ++ks) {
    half8 b0h[2], b0l[2], bsh[2], bsl[2];
    #pragma unroll
    for (int nt = 0; nt < 2; ++nt) {
      int t = (wave << 1) + nt;
      size_t fo = (((size_t)((t << 3) + ks) << 6) + lane) << 3;
      b0h[nt] = *(const half8*)&w0p[fo];
      b0l[nt] = *(const half8*)&w0lo[fo];
      bsh[nt] = *(const half8*)&wsp[fo];
      bsl[nt] = *(const half8*)&wslo[fo];
    }
    #pragma unroll
    for (int mt = 0; mt < 4; ++mt) {
      int kg = (mt << 3) + ks;
      int u = (kg << 6) + (lane ^ (kg & 7));
      half8 ah = *(const half8*)&Ahi[u << 3];
      half8 al = *(const half8*)&Alo[u << 3];
      half8 arh = relu8(ah, ah);
      half8 arl = relu8(ah, al);
      #pragma unroll
      for (int nt = 0; nt < 2; ++nt) {
        hm[mt][nt] = __builtin_amdgcn_mfma_f32_16x16x32_f16(arh, b0h[nt], hm[mt][nt], 0, 0, 0);
        hc[mt][nt] = __builtin_amdgcn_mfma_f32_16x16x32_f16(arl, b0h[nt], hc[mt][nt], 0, 0, 0);
        hc[mt][nt] = __builtin_amdgcn_mfma_f32_16x16x32_f16(arh, b0l[nt], hc[mt][nt], 0, 0, 0);
        so[mt][nt] = __builtin_amdgcn_mfma_f32_16x16x32_f16(ah,  bsh[nt], so[mt][nt], 0, 0, 0);
        sc[mt][nt] = __builtin_amdgcn_mfma_f32_16x16x32_f16(al,  bsh[nt], sc[mt][nt], 0, 0, 0);
        sc[mt][nt] = __builtin_amdgcn_mfma_f32_16x16x32_f16(ah,  bsl[nt], sc[mt][nt], 0, 0, 0);
      }
    }
  }
  __syncthreads();   // x planes dead; overlay h frags

  // ---- write relu(h) into A2 frag planes (K2 = 128) ----
  _Float16* A2hi = smem;                      // 8192 f16
  _Float16* A2lo = smem + 8192;
  {
    int q = lane >> 4, j2 = lane & 7, qh = (lane & 15) >> 3;
    #pragma unroll
    for (int mt = 0; mt < 4; ++mt) {
      int kg2 = (mt << 2) + wave;
      #pragma unroll
      for (int nt = 0; nt < 2; ++nt) {
        int quad2 = (nt << 1) + qh;
        #pragma unroll
        for (int r = 0; r < 4; ++r) {
          float hv = fmaxf(fmaf(hc[mt][nt][r], INV4096, hm[mt][nt][r]), 0.f);
          _Float16 hb, lb; splith(hv, hb, lb);
          int mm2 = (q << 2) + r;
          int ln2 = mm2 + (quad2 << 4);
          int u2 = (kg2 << 6) + (ln2 ^ (kg2 & 7));
          A2hi[(u2 << 3) + j2] = hb;
          A2lo[(u2 << 3) + j2] = lb;
        }
      }
    }
  }
  __syncthreads();

  // ---- GEMM1: s += relu(h) @ w1 ----
  const _Float16* w1lo = w1p + 16384;
  for (int ks = 0; ks < 4; ++ks) {
    half8 bh[2], bl[2];
    #pragma unroll
    for (int nt = 0; nt < 2; ++nt) {
      int t = (wave << 1) + nt;
      size_t fo = (((size_t)((t << 2) + ks) << 6) + lane) << 3;
      bh[nt] = *(const half8*)&w1p[fo];
      bl[nt] = *(const half8*)&w1lo[fo];
    }
    #pragma unroll
    for (int mt = 0; mt < 4; ++mt) {
      int kg = (mt << 2) + ks;
      int u = (kg << 6) + (lane ^ (kg & 7));
      half8 ah = *(const half8*)&A2hi[u << 3];
      half8 al = *(const half8*)&A2lo[u << 3];
      #pragma unroll
      for (int nt = 0; nt < 2; ++nt) {
        so[mt][nt] = __builtin_amdgcn_mfma_f32_16x16x32_f16(ah, bh[nt], so[mt][nt], 0, 0, 0);
        sc[mt][nt] = __builtin_amdgcn_mfma_f32_16x16x32_f16(al, bh[nt], sc[mt][nt], 0, 0, 0);
        sc[mt][nt] = __builtin_amdgcn_mfma_f32_16x16x32_f16(ah, bl[nt], sc[mt][nt], 0, 0, 0);
      }
    }
  }

  // ---- epilogue: store net (in-place rows) + fused max-pool ----
  {
    int col = lane & 15, q = lane >> 4;
    #pragma unroll
    for (int mt = 0; mt < 4; ++mt) {
      #pragma unroll
      for (int r = 0; r < 4; ++r) {
        int m_g = p0 + (mt << 4) + (q << 2) + r;
        int bi = 0;
        if (POOL) bi = ((b << 14) + idx[m_g]) << 7;
        #pragma unroll
        for (int nt = 0; nt < 2; ++nt) {
          int n = (wave << 5) + (nt << 4) + col;
          float v = fmaf(sc[mt][nt][r], INV4096, so[mt][nt][r]);
          net[(size_t)m_g * 128 + n] = v;
          if (POOL) atomicMax(&binsOut[bi + n], fenc(v));
        }
      }
    }
  }
}

// ---------- final linear (MFMA) + scatter-add ----------
__launch_bounds__(256, 2)
__global__ void k_fcc(const float* __restrict__ net, const int* __restrict__ idx,
                      const _Float16* __restrict__ fccp, const float* __restrict__ fccb,
                      float* __restrict__ sums) {
  extern __shared__ _Float16 smem[];          // 32 KB
  _Float16* Ahi = smem;
  _Float16* Alo = smem + 8192;
  const int tid = threadIdx.x, lane = tid & 63, wave = tid >> 6;
  const int p0 = blockIdx.x << 6, b = p0 >> 14;
  #pragma unroll
  for (int i = 0; i < 4; ++i) {
    int sidx = tid + (i << 8);
    int m = sidx >> 4, kslot = sidx & 15, k0 = kslot << 3;
    float4 a = *(const float4*)&net[(size_t)(p0 + m) * 128 + k0];
    float4 c = *(const float4*)&net[(size_t)(p0 + m) * 128 + k0 + 4];
    float v[8] = {fmaxf(a.x, 0.f), fmaxf(a.y, 0.f), fmaxf(a.z, 0.f), fmaxf(a.w, 0.f),
                  fmaxf(c.x, 0.f), fmaxf(c.y, 0.f), fmaxf(c.z, 0.f), fmaxf(c.w, 0.f)};
    half8 hi, lo; splith8(v, hi, lo);
    int mt = m >> 4, mm = m & 15, s = kslot >> 2, quad = kslot & 3;
    int ln = mm + (quad << 4), kg = (mt << 2) + s;
    int u = (kg << 6) + (ln ^ (kg & 7));
    *(half8*)&Ahi[u << 3] = hi;
    *(half8*)&Alo[u << 3] = lo;
  }
  __syncthreads();

  f32x4 am[4][2], ac[4][2];
  {
    int col = lane & 15;
    #pragma unroll
    for (int nt = 0; nt < 2; ++nt) {
      float bv = fccb[(wave << 5) + (nt << 4) + col];
      #pragma unroll
      for (int mt = 0; mt < 4; ++mt) {
        am[mt][nt] = (f32x4){bv, bv, bv, bv};
        ac[mt][nt] = (f32x4){0.f, 0.f, 0.f, 0.f};
      }
    }
  }
  const _Float16* flo = fccp + 16384;
  for (int ks = 0; ks < 4; ++ks) {
    half8 bh[2], bl[2];
    #pragma unroll
    for (int nt = 0; nt < 2; ++nt) {
      int t = (wave << 1) + nt;
      size_t fo = (((size_t)((t << 2) + ks) << 6) + lane) << 3;
      bh[nt] = *(const half8*)&fccp[fo];
      bl[nt] = *(const half8*)&flo[fo];
    }
    #pragma unroll
    for (int mt = 0; mt < 4; ++mt) {
      int kg = (mt << 2) + ks;
      int u = (kg << 6) + (lane ^ (kg & 7));
      half8 ah = *(const half8*)&Ahi[u << 3];
      half8 al = *(const half8*)&Alo[u << 3];
      #pragma unroll
      for (int nt = 0; nt < 2; ++nt) {
        am[mt][nt] = __builtin_amdgcn_mfma_f32_16x16x32_f16(ah, bh[nt], am[mt][nt], 0, 0, 0);
        ac[mt][nt] = __builtin_amdgcn_mfma_f32_16x16x32_f16(al, bh[nt], ac[mt][nt], 0, 0, 0);
        ac[mt][nt] = __builtin_amdgcn_mfma_f32_16x16x32_f16(ah, bl[nt], ac[mt][nt], 0, 0, 0);
      }
    }
  }
  {
    int col = lane & 15, q = lane >> 4;
    #pragma unroll
    for (int mt = 0; mt < 4; ++mt) {
      #pragma unroll
      for (int r = 0; r < 4; ++r) {
        int m_g = p0 + (mt << 4) + (q << 2) + r;
        int bi = ((b << 14) + idx[m_g]) << 7;
        #pragma unroll
        for (int nt = 0; nt < 2; ++nt) {
          int n = (wave << 5) + (nt << 4) + col;
          atomicAdd(&sums[bi + n], fmaf(ac[mt][nt][r], INV4096, am[mt][nt][r]));
        }
      }
    }
  }
}

// ---------- divide by counts + transpose (B,R2,C) -> (B,C,R2) ----------
__launch_bounds__(256)
__global__ void k_finalize(const float* __restrict__ sums, const float* __restrict__ cnt,
                           float* __restrict__ out) {
  __shared__ float t[64 * 65];
  __shared__ float rc[64];
  const int bid = blockIdx.x;                 // 4 * 256 * 2 = 2048
  const int ct = bid & 1, rt = (bid >> 1) & 255, b = bid >> 9;
  const int r0 = rt << 6, c0 = ct << 6;
  const int tid = threadIdx.x, l16 = tid & 15, sl = tid >> 4;
  for (int rr = sl; rr < 64; rr += 16) {
    float4 v = *(const float4*)&sums[(size_t)((b << 14) + r0 + rr) * 128 + c0 + (l16 << 2)];
    int cb = l16 << 2;
    t[rr * 65 + cb + 0] = v.x; t[rr * 65 + cb + 1] = v.y;
    t[rr * 65 + cb + 2] = v.z; t[rr * 65 + cb + 3] = v.w;
  }
  if (tid < 64) rc[tid] = 1.f / fmaxf(cnt[(b << 14) + r0 + tid], 1.f);
  __syncthreads();
  for (int cc = sl; cc < 64; cc += 16) {
    int c = c0 + cc;
    int rb = l16 << 2;
    float4 o = make_float4(t[(rb + 0) * 65 + cc] * rc[rb + 0],
                           t[(rb + 1) * 65 + cc] * rc[rb + 1],
                           t[(rb + 2) * 65 + cc] * rc[rb + 2],
                           t[(rb + 3) * 65 + cc] * rc[rb + 3]);
    *(float4*)&out[(size_t)((b << 7) + c) * 16384 + r0 + rb] = o;
  }
}

// ---------- host launch ----------
extern "C" void kernel_launch(void* const* d_in, const int* in_sizes, int n_in,
                              void* d_out, int out_size, void* d_ws, size_t ws_size,
                              hipStream_t stream) {
  const float* points = (const float*)d_in[0];
  const float* posw   = (const float*)d_in[1];
  const float* posb   = (const float*)d_in[2];
  const float* fc0w   = (const float*)d_in[3];
  const float* fc0b   = (const float*)d_in[4];
  const float* fc1w   = (const float*)d_in[5];
  const float* fc1b   = (const float*)d_in[6];
  const float* scw    = (const float*)d_in[7];
  const float* fccw   = (const float*)d_in[8];
  const float* fccb   = (const float*)d_in[9];
  float* outp = (float*)d_out;

  // workspace: net 32MB | bins0 32MB | bins1 32MB | idx | cnt | packed weights
  float* net = (float*)d_ws;
  unsigned* bins0 = (unsigned*)(net + (size_t)BN * 128);
  unsigned* bins1 = bins0 + (size_t)8388608;
  int* idxp = (int*)(bins1 + (size_t)8388608);
  float* cnt = (float*)(idxp + BN);
  _Float16* wp = (_Float16*)(cnt + 65536);

  const _Float16* w0_ = wp;            // 5 x 65536 (hi|lo)
  const _Float16* ws_ = wp + 327680;   // 5 x 65536
  const _Float16* w1_ = wp + 655360;   // 5 x 32768
  const _Float16* fcc_ = wp + 819200;  // 32768

  k_zero4<<<64, 256, 0, stream>>>((float4*)cnt, 16384);
  k_idx<<<256, 256, 0, stream>>>(points, idxp, cnt);
  k_pack<<<208, 256, 0, stream>>>(fc0w, scw, fc1w, fccw, wp);

  k_zero4<<<8192, 256, 0, stream>>>((float4*)bins0, 2097152);
  k_rb<0, 1><<<1024, 256, 65536, stream>>>(points, nullptr, bins0, idxp, posw, posb,
                                           w0_, fc0b, w1_, fc1b, ws_, net);
  unsigned* bin_in = bins0;
  unsigned* bin_out = bins1;
  for (int l = 1; l < 4; ++l) {
    k_zero4<<<8192, 256, 0, stream>>>((float4*)bin_out, 2097152);
    k_rb<1, 1><<<1024, 256, 65536, stream>>>(points, bin_in, bin_out, idxp, posw, posb,
                                             w0_ + (size_t)l * 65536, fc0b + l * 128,
                                             w1_ + (size_t)l * 32768, fc1b + l * 128,
                                             ws_ + (size_t)l * 65536, net);
    unsigned* tsw = bin_in; bin_in = bin_out; bin_out = tsw;
  }
  // layer 4: no pooling; bin_out (the buffer not read by layer 4) becomes sums
  k_zero4<<<8192, 256, 0, stream>>>((float4*)bin_out, 2097152);
  k_rb<1, 0><<<1024, 256, 65536, stream>>>(points, bin_in, nullptr, idxp, posw, posb,
                                           w0_ + (size_t)4 * 65536, fc0b + 4 * 128,
                                           w1_ + (size_t)4 * 32768, fc1b + 4 * 128,
                                           ws_ + (size_t)4 * 65536, net);
  float* sums = (float*)bin_out;
  k_fcc<<<1024, 256, 32768, stream>>>(net, idxp, fcc_, fccb, sums);
  k_finalize<<<2048, 256, 0, stream>>>(sums, cnt, outp);
}